// Round 9
// baseline (202.970 us; speedup 1.0000x reference)
//
#include <hip/hip_runtime.h>
#include <hip/hip_bf16.h>

// Problem: B=64, S=512, D=512.
// out[b] = (sum_{valid i} max_{valid j} sim[i,j] + sum_{valid j} max_{valid i} sim[i,j]) / (n1+n2)
// sim = normalize(e1) @ normalize(e2)^T per batch.
//
// Round-16: r8 proved the split (prep -> bf16 panels -> gload_lds GEMM):
// sim_gemm ~30us (vs 69.7 fused). prep was 56us at 2.4TB/s with VGPR=24 --
// the compiler serialized the per-row load->reduce->store chain (r7's
// pathology). This round rewrites ONLY prep for explicit ILP:
//   * 2048 blocks (XCD-bijective), 8 rows/wave (was 16)
//   * rows in explicit groups of 4: all loads issued first, 4 interleaved
//     shuffle-reduce chains, then 4 stores -- static indexing throughout
//   * identical fp32 math + identical swizzled-store formula (r8-verified)
// sim_gemm / fallback / final unchanged (controls).
// ws: 1 MB partials + 64 MB bf16 panels.

typedef __attribute__((ext_vector_type(8))) short bf16x8;   // 8 bf16 in 4 VGPRs
typedef __attribute__((ext_vector_type(4))) float f32x4;

#define NEGBIG (-1e9f)

__device__ __forceinline__ unsigned packbf2_hw(float lo, float hi) {
    __hip_bfloat162 h = __float22bfloat162_rn(float2{lo, hi});
    union { __hip_bfloat162 h; unsigned u; } c; c.h = h;
    return c.u;
}

// lgkm-only barrier (ds_write visibility; globals stay in flight)
#define BAR() do {                                            \
        asm volatile("s_waitcnt lgkmcnt(0)" ::: "memory");    \
        __builtin_amdgcn_s_barrier();                         \
        asm volatile("" ::: "memory");                        \
    } while (0)

// vmcnt-drain barrier (gload_lds path: DMA completion tracked by vmcnt)
#define BARV() do {                                           \
        asm volatile("s_waitcnt vmcnt(0)" ::: "memory");      \
        __builtin_amdgcn_s_barrier();                         \
        asm volatile("" ::: "memory");                        \
    } while (0)

__device__ __forceinline__ void glds16(const ushort* g, ushort* l) {
    __builtin_amdgcn_global_load_lds(
        (const __attribute__((address_space(1))) unsigned int*)(const void*)g,
        (__attribute__((address_space(3))) unsigned int*)(void*)l,
        16, 0, 0);
}

// ---------------- kernel 0: normalize + cast + pre-swizzle (ILP v2) --------
// grid 2048 (XCD-swizzled), 256 thr = 4 waves. Block = (batch b, idx 0..31):
// idx<16 -> e1 rows [(idx&15)*32, +32), else e2. Wave w: 8 rows, in 2 groups
// of 4 with explicit load-all / reduce-interleaved / store-all phasing.
// Output chunk c (8 bf16) of row r stored at slot c^s(r) within its 32-k
// group, s(r) = (r ^ (r>>2)) & 3  -> linear gload_lds lands r5's LDS layout.
__global__ __launch_bounds__(256)
void prep_kernel(const float* __restrict__ e1, const float* __restrict__ e2,
                 ushort* __restrict__ e1n, ushort* __restrict__ e2n)
{
    const int bid = blockIdx.x;
    const int l   = ((bid & 7) << 8) | (bid >> 3);   // bijective, 2048 = 8*256
    const int b   = l >> 5;                          // 0..63
    const int idx = l & 31;                          // 0..31
    const int lane = threadIdx.x & 63;
    const int w    = threadIdx.x >> 6;
    const float*  src = (idx < 16) ? e1 : e2;
    ushort*       dst = (idx < 16) ? e1n : e2n;
    const int rbase = (idx & 15) * 32 + w * 8;

    // store offset pieces that don't depend on the row
    const int kgrp = (lane >> 2) * 32;   // 32-ushort k-group base
    const int chnk = lane & 3;           // chunk within group

    #pragma unroll
    for (int g = 0; g < 2; ++g) {
        const int r0 = rbase + g * 4;
        // ---- phase 1: issue all 8 loads (4 rows x 2 float4)
        float4 xa0, ya0, xa1, ya1, xa2, ya2, xa3, ya3;
        const size_t o0 = ((size_t)b * 512 + r0 + 0) * 512;
        const size_t o1 = ((size_t)b * 512 + r0 + 1) * 512;
        const size_t o2 = ((size_t)b * 512 + r0 + 2) * 512;
        const size_t o3 = ((size_t)b * 512 + r0 + 3) * 512;
        {
            const float4* p0 = reinterpret_cast<const float4*>(src + o0) + lane * 2;
            const float4* p1 = reinterpret_cast<const float4*>(src + o1) + lane * 2;
            const float4* p2 = reinterpret_cast<const float4*>(src + o2) + lane * 2;
            const float4* p3 = reinterpret_cast<const float4*>(src + o3) + lane * 2;
            xa0 = p0[0]; ya0 = p0[1];
            xa1 = p1[0]; ya1 = p1[1];
            xa2 = p2[0]; ya2 = p2[1];
            xa3 = p3[0]; ya3 = p3[1];
        }
        // ---- phase 2: local sums (independent), interleaved butterflies
        float s0 = xa0.x*xa0.x + xa0.y*xa0.y + xa0.z*xa0.z + xa0.w*xa0.w
                 + ya0.x*ya0.x + ya0.y*ya0.y + ya0.z*ya0.z + ya0.w*ya0.w;
        float s1 = xa1.x*xa1.x + xa1.y*xa1.y + xa1.z*xa1.z + xa1.w*xa1.w
                 + ya1.x*ya1.x + ya1.y*ya1.y + ya1.z*ya1.z + ya1.w*ya1.w;
        float s2 = xa2.x*xa2.x + xa2.y*xa2.y + xa2.z*xa2.z + xa2.w*xa2.w
                 + ya2.x*ya2.x + ya2.y*ya2.y + ya2.z*ya2.z + ya2.w*ya2.w;
        float s3 = xa3.x*xa3.x + xa3.y*xa3.y + xa3.z*xa3.z + xa3.w*xa3.w
                 + ya3.x*ya3.x + ya3.y*ya3.y + ya3.z*ya3.z + ya3.w*ya3.w;
        #pragma unroll
        for (int m = 1; m < 64; m <<= 1) {
            s0 += __shfl_xor(s0, m);
            s1 += __shfl_xor(s1, m);
            s2 += __shfl_xor(s2, m);
            s3 += __shfl_xor(s3, m);
        }
        const float i0 = 1.0f / fmaxf(sqrtf(s0), 1e-8f);
        const float i1 = 1.0f / fmaxf(sqrtf(s1), 1e-8f);
        const float i2 = 1.0f / fmaxf(sqrtf(s2), 1e-8f);
        const float i3 = 1.0f / fmaxf(sqrtf(s3), 1e-8f);
        // ---- phase 3: scale + pack + swizzled store, 4 rows
#define STORE_ROW(XX, YY, II, OO, RI)                                       \
        do {                                                                \
            uint4 v;                                                        \
            v.x = packbf2_hw(XX.x * II, XX.y * II);                         \
            v.y = packbf2_hw(XX.z * II, XX.w * II);                         \
            v.z = packbf2_hw(YY.x * II, YY.y * II);                         \
            v.w = packbf2_hw(YY.z * II, YY.w * II);                         \
            const int row = r0 + (RI);                                      \
            const int s   = (row ^ (row >> 2)) & 3;                         \
            *reinterpret_cast<uint4*>(dst + OO + kgrp + ((chnk ^ s) << 3)) = v; \
        } while (0)
        STORE_ROW(xa0, ya0, i0, o0, 0);
        STORE_ROW(xa1, ya1, i1, o1, 1);
        STORE_ROW(xa2, ya2, i2, o2, 2);
        STORE_ROW(xa3, ya3, i3, o3, 3);
#undef STORE_ROW
    }
}

// ---------------- kernel 1: bf16 GEMM + masked-max (gload_lds) ----------------
// grid 1024 (XCD-swizzled), 256 thr = 4 waves (2x2 of 64x64). 128x128 tile,
// BK=32, double-buffered LDS staged by global_load_lds dwordx4 (linear dest;
// source pre-swizzled by prep). Frag offsets identical to r5 (proven).
__global__ __launch_bounds__(256)
void sim_gemm(const ushort* __restrict__ e1n, const ushort* __restrict__ e2n,
              const int* __restrict__ m1g, const int* __restrict__ m2g,
              float* __restrict__ rowmax_p, float* __restrict__ colmax_p)
{
    const int bid = blockIdx.x;
    const int l   = ((bid & 7) << 7) | (bid >> 3);
    const int b   = l >> 4;
    const int rt  = l & 3;
    const int ct  = (l >> 2) & 3;

    const int tid  = threadIdx.x;
    const int lane = tid & 63;
    const int w    = tid >> 6;        // 0..3
    const int wm   = w >> 1;
    const int wn   = w & 1;
    const int q    = lane >> 4;
    const int ln   = lane & 15;
    const int nb   = ct * 128;

    __shared__ __align__(16) ushort sA[2][128 * 32];   // 2 x 8 KB
    __shared__ __align__(16) ushort sB[2][128 * 32];   // 2 x 8 KB
    float* spr = reinterpret_cast<float*>(&sA[0][0]);     // [2][128]
    float* spc = reinterpret_cast<float*>(&sA[0][512]);   // [2][128]
    int*   sm1 = reinterpret_cast<int*>(&sA[0][1024]);    // [128]
    int*   sm2 = reinterpret_cast<int*>(&sA[0][1280]);    // [128]

    // ---- staging: wave w stages A-chunks 2w,2w+1 and B-chunks 2w,2w+1.
    // Chunk ch = 16 rows x 32 k (1KB). lane l -> row ch*16+(l>>2),
    // k-ushort (l&3)*8; LDS dest = chunk base + l*16 bytes (linear).
    const int rs = lane >> 2;
    const int ks = (lane & 3) * 8;
    const ushort* gA0 = e1n + ((size_t)(b * 512 + rt * 128 + 2 * w * 16 + rs)) * 512 + ks;
    const ushort* gA1 = gA0 + 16 * 512;
    const ushort* gB0 = e2n + ((size_t)(b * 512 + nb + 2 * w * 16 + rs)) * 512 + ks;
    const ushort* gB1 = gB0 + 16 * 512;
    const int dch = w * 1024;          // chunk-pair base (ushorts)

    // ---- fragment read offsets (identical to r5; slot = chunk ^ s(row))
    const int sln = (ln & 3) ^ ((ln >> 2) & 3);
    int aoff[4], boff[4];
    #pragma unroll
    for (int mt = 0; mt < 4; ++mt)
        aoff[mt] = (wm * 64 + mt * 16 + ln) * 32 + ((q ^ sln) << 3);
    #pragma unroll
    for (int nt = 0; nt < 4; ++nt)
        boff[nt] = (wn * 64 + nt * 16 + ln) * 32 + ((q ^ sln) << 3);

    f32x4 acc[4][4];
    #pragma unroll
    for (int i = 0; i < 4; ++i)
        #pragma unroll
        for (int j = 0; j < 4; ++j)
            acc[i][j] = (f32x4){0.f, 0.f, 0.f, 0.f};

#define STAGE(P2, KT)                                                       \
    do {                                                                    \
        const int k32 = (KT) * 32;                                          \
        glds16(gA0 + k32, &sA[P2][dch]);                                    \
        glds16(gA1 + k32, &sA[P2][dch + 512]);                              \
        glds16(gB0 + k32, &sB[P2][dch]);                                    \
        glds16(gB1 + k32, &sB[P2][dch + 512]);                              \
    } while (0)

    STAGE(0, 0);
    BARV();

#define ITER(P, K)                                                          \
    do {                                                                    \
        if ((K) < 15) STAGE((P) ^ 1, (K) + 1);                              \
        bf16x8 af[4], bfr[4];                                               \
        _Pragma("unroll")                                                   \
        for (int mt = 0; mt < 4; ++mt)                                      \
            af[mt] = *reinterpret_cast<const bf16x8*>(&sA[P][aoff[mt]]);    \
        _Pragma("unroll")                                                   \
        for (int nt = 0; nt < 4; ++nt)                                      \
            bfr[nt] = *reinterpret_cast<const bf16x8*>(&sB[P][boff[nt]]);   \
        _Pragma("unroll")                                                   \
        for (int mt = 0; mt < 4; ++mt)                                      \
            _Pragma("unroll")                                               \
            for (int nt = 0; nt < 4; ++nt)                                  \
                acc[mt][nt] = __builtin_amdgcn_mfma_f32_16x16x32_bf16(      \
                    af[mt], bfr[nt], acc[mt][nt], 0, 0, 0);                 \
        BARV();                                                             \
    } while (0)

    for (int kk = 0; kk < 8; ++kk) {
        ITER(0, 2 * kk);
        ITER(1, 2 * kk + 1);
    }
#undef ITER
#undef STAGE

    // ---- masks into dead tile space (no norm work: inputs pre-normalized)
    if (tid < 128) sm1[tid] = m1g[b * 512 + rt * 128 + tid];
    else           sm2[tid - 128] = m2g[b * 512 + nb + (tid - 128)];
    BAR();

    // ---- masked row maxes (C/D layout: col=ln, row=q*4+reg)
    #pragma unroll
    for (int mt = 0; mt < 4; ++mt) {
        #pragma unroll
        for (int rg = 0; rg < 4; ++rg) {
            float rm = NEGBIG;
            #pragma unroll
            for (int nt = 0; nt < 4; ++nt) {
                float v = sm2[wn * 64 + nt * 16 + ln] ? acc[mt][nt][rg] : NEGBIG;
                rm = fmaxf(rm, v);
            }
            rm = fmaxf(rm, __shfl_xor(rm, 1));
            rm = fmaxf(rm, __shfl_xor(rm, 2));
            rm = fmaxf(rm, __shfl_xor(rm, 4));
            rm = fmaxf(rm, __shfl_xor(rm, 8));
            if (ln == 0) spr[wn * 128 + wm * 64 + mt * 16 + q * 4 + rg] = rm;
        }
    }
    #pragma unroll
    for (int nt = 0; nt < 4; ++nt) {
        float cm = NEGBIG;
        #pragma unroll
        for (int mt = 0; mt < 4; ++mt)
            #pragma unroll
            for (int rg = 0; rg < 4; ++rg) {
                float v = sm1[wm * 64 + mt * 16 + q * 4 + rg] ? acc[mt][nt][rg] : NEGBIG;
                cm = fmaxf(cm, v);
            }
        cm = fmaxf(cm, __shfl_xor(cm, 16));
        cm = fmaxf(cm, __shfl_xor(cm, 32));
        if (lane < 16) spc[wm * 128 + wn * 64 + nt * 16 + ln] = cm;
    }
    BAR();
    if (tid < 128) {
        rowmax_p[((size_t)b * 4 + ct) * 512 + rt * 128 + tid] =
            fmaxf(spr[tid], spr[128 + tid]);
        colmax_p[((size_t)b * 4 + rt) * 512 + nb + tid] =
            fmaxf(spc[tid], spc[128 + tid]);
    }
}

// ---------------- fallback: r5 fused kernel (verbatim) ----------------
__global__ __launch_bounds__(256)
void sim_fused_fb(const float* __restrict__ e1, const float* __restrict__ e2,
                  const int* __restrict__ m1g, const int* __restrict__ m2g,
                  float* __restrict__ rowmax_p, float* __restrict__ colmax_p)
{
    const int bid = blockIdx.x;
    const int l   = ((bid & 7) << 7) | (bid >> 3);
    const int b   = l >> 4;
    const int rt  = l & 3;
    const int ct  = (l >> 2) & 3;

    const int tid = threadIdx.x;
    const int lane = tid & 63;
    const int w    = tid >> 6;
    const int wm   = w >> 1;
    const int wn   = w & 1;
    const int q    = lane >> 4;
    const int ln   = lane & 15;
    const int nb   = ct * 128;

    __shared__ __align__(16) ushort sA[2][128 * 32];
    __shared__ __align__(16) ushort sB[2][128 * 32];
    float* spr   = reinterpret_cast<float*>(&sA[0][0]);
    float* spc   = reinterpret_cast<float*>(&sA[0][512]);
    int*   sm1   = reinterpret_cast<int*>(&sA[0][1024]);
    int*   sm2   = reinterpret_cast<int*>(&sA[0][1280]);
    float* sinv1 = reinterpret_cast<float*>(&sB[0][0]);
    float* sinv2 = reinterpret_cast<float*>(&sB[0][256]);

    const int r = tid >> 1;
    const int h = tid & 1;
    const int s = (r ^ (r >> 2)) & 3;
    const float* gA = e1 + ((size_t)(b * 512 + rt * 128 + r)) * 512 + h * 16;
    const float* gB = e2 + ((size_t)(b * 512 + nb + r)) * 512 + h * 16;
    const int wo0 = r * 32 + (((2 * h)     ^ s) << 3);
    const int wo1 = r * 32 + (((2 * h + 1) ^ s) << 3);

    const int sln = (ln & 3) ^ ((ln >> 2) & 3);
    int aoff[4], boff[4];
    #pragma unroll
    for (int mt = 0; mt < 4; ++mt)
        aoff[mt] = (wm * 64 + mt * 16 + ln) * 32 + ((q ^ sln) << 3);
    #pragma unroll
    for (int nt = 0; nt < 4; ++nt)
        boff[nt] = (wn * 64 + nt * 16 + ln) * 32 + ((q ^ sln) << 3);

    float ssA = 0.f, ssB = 0.f;
    float4 ra[2][4], rb[2][4];

    auto LOADK = [&](int u, int kf) {
        const float4* pa = reinterpret_cast<const float4*>(gA + kf);
        const float4* pb = reinterpret_cast<const float4*>(gB + kf);
        ra[u][0] = pa[0]; ra[u][1] = pa[1]; ra[u][2] = pa[2]; ra[u][3] = pa[3];
        rb[u][0] = pb[0]; rb[u][1] = pb[1]; rb[u][2] = pb[2]; rb[u][3] = pb[3];
    };
    auto CVTWRITE = [&](int u, int pd) {
        #pragma unroll
        for (int i = 0; i < 4; ++i) {
            ssA += ra[u][i].x * ra[u][i].x + ra[u][i].y * ra[u][i].y
                 + ra[u][i].z * ra[u][i].z + ra[u][i].w * ra[u][i].w;
            ssB += rb[u][i].x * rb[u][i].x + rb[u][i].y * rb[u][i].y
                 + rb[u][i].z * rb[u][i].z + rb[u][i].w * rb[u][i].w;
        }
        uint4 v;
        v.x = packbf2_hw(ra[u][0].x, ra[u][0].y); v.y = packbf2_hw(ra[u][0].z, ra[u][0].w);
        v.z = packbf2_hw(ra[u][1].x, ra[u][1].y); v.w = packbf2_hw(ra[u][1].z, ra[u][1].w);
        *reinterpret_cast<uint4*>(&sA[pd][wo0]) = v;
        v.x = packbf2_hw(ra[u][2].x, ra[u][2].y); v.y = packbf2_hw(ra[u][2].z, ra[u][2].w);
        v.z = packbf2_hw(ra[u][3].x, ra[u][3].y); v.w = packbf2_hw(ra[u][3].z, ra[u][3].w);
        *reinterpret_cast<uint4*>(&sA[pd][wo1]) = v;
        v.x = packbf2_hw(rb[u][0].x, rb[u][0].y); v.y = packbf2_hw(rb[u][0].z, rb[u][0].w);
        v.z = packbf2_hw(rb[u][1].x, rb[u][1].y); v.w = packbf2_hw(rb[u][1].z, rb[u][1].w);
        *reinterpret_cast<uint4*>(&sB[pd][wo0]) = v;
        v.x = packbf2_hw(rb[u][2].x, rb[u][2].y); v.y = packbf2_hw(rb[u][2].z, rb[u][2].w);
        v.z = packbf2_hw(rb[u][3].x, rb[u][3].y); v.w = packbf2_hw(rb[u][3].z, rb[u][3].w);
        *reinterpret_cast<uint4*>(&sB[pd][wo1]) = v;
    };

    f32x4 acc[4][4];
    #pragma unroll
    for (int i = 0; i < 4; ++i)
        #pragma unroll
        for (int j = 0; j < 4; ++j)
            acc[i][j] = (f32x4){0.f, 0.f, 0.f, 0.f};

    LOADK(0, 0);
    CVTWRITE(0, 0);
    LOADK(1, 32);
    BAR();

#define HALF_ITER(P, K)                                                    \
    do {                                                                   \
        if ((K) < 14) LOADK(P, ((K) + 2) * 32);                            \
        bf16x8 af[4], bfr[4];                                              \
        _Pragma("unroll")                                                  \
        for (int mt = 0; mt < 4; ++mt)                                     \
            af[mt] = *reinterpret_cast<const bf16x8*>(&sA[P][aoff[mt]]);   \
        _Pragma("unroll")                                                  \
        for (int nt = 0; nt < 4; ++nt)                                     \
            bfr[nt] = *reinterpret_cast<const bf16x8*>(&sB[P][boff[nt]]);  \
        if ((K) < 15) CVTWRITE((P) ^ 1, (P) ^ 1);                          \
        _Pragma("unroll")                                                  \
        for (int mt = 0; mt < 4; ++mt)                                     \
            _Pragma("unroll")                                              \
            for (int nt = 0; nt < 4; ++nt)                                 \
                acc[mt][nt] = __builtin_amdgcn_mfma_f32_16x16x32_bf16(     \
                    af[mt], bfr[nt], acc[mt][nt], 0, 0, 0);                \
        BAR();                                                             \
    } while (0)

    for (int kk = 0; kk < 8; ++kk) {
        HALF_ITER(0, 2 * kk);
        HALF_ITER(1, 2 * kk + 1);
    }
#undef HALF_ITER

    if (tid < 128) sm1[tid] = m1g[b * 512 + rt * 128 + tid];
    else           sm2[tid - 128] = m2g[b * 512 + nb + (tid - 128)];
    ssA += __shfl_xor(ssA, 1);
    ssB += __shfl_xor(ssB, 1);
    if (h == 0) {
        sinv1[r] = 1.0f / fmaxf(sqrtf(ssA), 1e-8f);
        sinv2[r] = 1.0f / fmaxf(sqrtf(ssB), 1e-8f);
    }
    BAR();

    float invj[4];
    f32x4 invi[4];
    #pragma unroll
    for (int nt = 0; nt < 4; ++nt)
        invj[nt] = sinv2[wn * 64 + nt * 16 + ln];
    #pragma unroll
    for (int mt = 0; mt < 4; ++mt)
        #pragma unroll
        for (int rg = 0; rg < 4; ++rg)
            invi[mt][rg] = sinv1[wm * 64 + mt * 16 + q * 4 + rg];
    #pragma unroll
    for (int mt = 0; mt < 4; ++mt)
        #pragma unroll
        for (int nt = 0; nt < 4; ++nt)
            acc[mt][nt] = acc[mt][nt] * (invi[mt] * invj[nt]);

    #pragma unroll
    for (int mt = 0; mt < 4; ++mt) {
        #pragma unroll
        for (int rg = 0; rg < 4; ++rg) {
            float rm = NEGBIG;
            #pragma unroll
            for (int nt = 0; nt < 4; ++nt) {
                float v = sm2[wn * 64 + nt * 16 + ln] ? acc[mt][nt][rg] : NEGBIG;
                rm = fmaxf(rm, v);
            }
            rm = fmaxf(rm, __shfl_xor(rm, 1));
            rm = fmaxf(rm, __shfl_xor(rm, 2));
            rm = fmaxf(rm, __shfl_xor(rm, 4));
            rm = fmaxf(rm, __shfl_xor(rm, 8));
            if (ln == 0) spr[wn * 128 + wm * 64 + mt * 16 + q * 4 + rg] = rm;
        }
    }
    #pragma unroll
    for (int nt = 0; nt < 4; ++nt) {
        float cm = NEGBIG;
        #pragma unroll
        for (int mt = 0; mt < 4; ++mt)
            #pragma unroll
            for (int rg = 0; rg < 4; ++rg) {
                float v = sm1[wm * 64 + mt * 16 + q * 4 + rg] ? acc[mt][nt][rg] : NEGBIG;
                cm = fmaxf(cm, v);
            }
        cm = fmaxf(cm, __shfl_xor(cm, 16));
        cm = fmaxf(cm, __shfl_xor(cm, 32));
        if (lane < 16) spc[wm * 128 + wn * 64 + nt * 16 + ln] = cm;
    }
    BAR();
    if (tid < 128) {
        rowmax_p[((size_t)b * 4 + ct) * 512 + rt * 128 + tid] =
            fmaxf(spr[tid], spr[128 + tid]);
        colmax_p[((size_t)b * 4 + rt) * 512 + nb + tid] =
            fmaxf(spc[tid], spc[128 + tid]);
    }
}

// ---------------- kernel 2: per-batch final reduction ----------------
__global__ __launch_bounds__(256)
void final_kernel(const int* __restrict__ m1g, const int* __restrict__ m2g,
                  const float* __restrict__ rowmax_p, const float* __restrict__ colmax_p,
                  float* __restrict__ out)
{
    const int b = blockIdx.x;
    const int tid = threadIdx.x;
    const int lane = tid & 63;
    const int w = tid >> 6;

    float sum = 0.f;
    float nn  = 0.f;
    for (int j = tid; j < 512; j += 256) {
        int mm1 = m1g[b * 512 + j];
        int mm2 = m2g[b * 512 + j];
        nn += (float)(mm1 + mm2);
        const float* rp = rowmax_p + (size_t)b * 2048 + j;
        float rm = fmaxf(fmaxf(rp[0], rp[512]), fmaxf(rp[1024], rp[1536]));
        if (mm1) sum += rm;
        const float* cp = colmax_p + (size_t)b * 2048 + j;
        float cm = fmaxf(fmaxf(cp[0], cp[512]), fmaxf(cp[1024], cp[1536]));
        if (mm2) sum += cm;
    }
    #pragma unroll
    for (int m = 32; m; m >>= 1) {
        sum += __shfl_xor(sum, m);
        nn  += __shfl_xor(nn, m);
    }
    __shared__ float ssum[4], snn[4];
    if (lane == 0) { ssum[w] = sum; snn[w] = nn; }
    __syncthreads();
    if (tid == 0) {
        float S = ssum[0] + ssum[1] + ssum[2] + ssum[3];
        float N = snn[0] + snn[1] + snn[2] + snn[3];
        out[b] = S / N;
    }
}

extern "C" void kernel_launch(void* const* d_in, const int* in_sizes, int n_in,
                              void* d_out, int out_size, void* d_ws, size_t ws_size,
                              hipStream_t stream) {
    const float* e1 = (const float*)d_in[0];
    const float* e2 = (const float*)d_in[1];
    const int*   m1 = (const int*)d_in[2];
    const int*   m2 = (const int*)d_in[3];
    float* out = (float*)d_out;

    float* ws = (float*)d_ws;
    float* rowmax_p = ws;                 // 64*4*512 floats
    float* colmax_p = ws + 131072;        // 64*4*512 floats

    const size_t PANEL = (size_t)64 * 512 * 512;            // ushort count
    const size_t NEED  = 1048576 + 2 * PANEL * sizeof(ushort);  // ~68.1 MB

    if (ws_size >= NEED) {
        ushort* e1n = (ushort*)((char*)d_ws + 1048576);
        ushort* e2n = e1n + PANEL;
        prep_kernel<<<dim3(2048), 256, 0, stream>>>(e1, e2, e1n, e2n);
        sim_gemm<<<dim3(1024), 256, 0, stream>>>(e1n, e2n, m1, m2,
                                                 rowmax_p, colmax_p);
    } else {
        sim_fused_fb<<<dim3(1024), 256, 0, stream>>>(e1, e2, m1, m2,
                                                     rowmax_p, colmax_p);
    }
    final_kernel<<<64, 256, 0, stream>>>(m1, m2, rowmax_p, colmax_p, out);
}

// Round 10
// 197.832 us; speedup vs baseline: 1.0260x; 1.0260x over previous
//
#include <hip/hip_runtime.h>
#include <hip/hip_bf16.h>

// Problem: B=64, S=512, D=512.
// out[b] = (sum_{valid i} max_{valid j} sim[i,j] + sum_{valid j} max_{valid i} sim[i,j]) / (n1+n2)
// sim = normalize(e1) @ normalize(e2)^T per batch.
//
// Round-17: prep with asm-FORCED load pipelining. r8 (24 VGPR, 56us) and r9
// (32 VGPR, 68us) prove the register allocator re-serializes any source-level
// load phasing in this memory-bound kernel; Little's law says bytes-in-flight
// per wave is the only lever (need ~256B/wave for ~5TB/s at ~700cy latency,
// compiler gives 32B). Fix: 16 global_load_dwordx4 per wave issued as inline
// asm with "=v" outputs (allocator MUST keep them), consumed under counted
// s_waitcnt vmcnt(N) asm with "+v" register ties (rule-18: ordering via data
// dep, not memory clobber). Identical math + swizzled-store formula to r8/r9
// (absmax 0.0 verified). sim_gemm / fallback / final unchanged (controls).
// ws: 1 MB partials + 64 MB bf16 panels.

typedef __attribute__((ext_vector_type(8))) short bf16x8;   // 8 bf16 in 4 VGPRs
typedef __attribute__((ext_vector_type(4))) float f32x4;

#define NEGBIG (-1e9f)

__device__ __forceinline__ unsigned packbf2_hw(float lo, float hi) {
    __hip_bfloat162 h = __float22bfloat162_rn(float2{lo, hi});
    union { __hip_bfloat162 h; unsigned u; } c; c.h = h;
    return c.u;
}

// lgkm-only barrier (ds_write visibility; globals stay in flight)
#define BAR() do {                                            \
        asm volatile("s_waitcnt lgkmcnt(0)" ::: "memory");    \
        __builtin_amdgcn_s_barrier();                         \
        asm volatile("" ::: "memory");                        \
    } while (0)

// vmcnt-drain barrier (gload_lds path: DMA completion tracked by vmcnt)
#define BARV() do {                                           \
        asm volatile("s_waitcnt vmcnt(0)" ::: "memory");      \
        __builtin_amdgcn_s_barrier();                         \
        asm volatile("" ::: "memory");                        \
    } while (0)

__device__ __forceinline__ void glds16(const ushort* g, ushort* l) {
    __builtin_amdgcn_global_load_lds(
        (const __attribute__((address_space(1))) unsigned int*)(const void*)g,
        (__attribute__((address_space(3))) unsigned int*)(void*)l,
        16, 0, 0);
}

// ---------------- kernel 0: normalize + cast + pre-swizzle (asm-ILP) -------
// grid 2048 (XCD-swizzled), 256 thr = 4 waves. Block = (batch b, idx 0..31):
// idx<16 -> e1 rows [(idx&15)*32 + w*8, +8), else e2. 8 rows/wave; all 16
// loads (8 rows x 32B) in flight simultaneously via asm; counted vmcnt drain.
// Output chunk c (8 bf16) of row r stored at slot c^s(r) within its 32-k
// group, s(r) = (r ^ (r>>2)) & 3  -> linear gload_lds lands r5's LDS layout.
__global__ __launch_bounds__(256)
void prep_kernel(const float* __restrict__ e1, const float* __restrict__ e2,
                 ushort* __restrict__ e1n, ushort* __restrict__ e2n)
{
    const int bid = blockIdx.x;
    const int l   = ((bid & 7) << 8) | (bid >> 3);   // bijective, 2048 = 8*256
    const int b   = l >> 5;                          // 0..63
    const int idx = l & 31;                          // 0..31
    const int lane = threadIdx.x & 63;
    const int w    = threadIdx.x >> 6;
    const float*  src = (idx < 16) ? e1 : e2;
    ushort*       dst = (idx < 16) ? e1n : e2n;
    const int rbase = (idx & 15) * 32 + w * 8;

    const int kgrp = (lane >> 2) * 32;   // 32-ushort k-group base
    const int chnk = lane & 3;           // chunk within group

    const size_t obase = ((size_t)b * 512 + rbase) * 512;
    const float* a0 = src + obase + lane * 8;   // lane's 32B slice of row 0

    f32x4 x0, y0, x1, y1, x2, y2, x3, y3, x4, y4, x5, y5, x6, y6, x7, y7;

    // ---- phase 1: issue all 16 loads (asm outputs -> allocator must keep)
#define ISSUE(XV, YV, R)                                                    \
    asm volatile("global_load_dwordx4 %0, %2, off\n\t"                      \
                 "global_load_dwordx4 %1, %2, off offset:16"                \
                 : "=v"(XV), "=v"(YV)                                       \
                 : "v"(a0 + (R) * 512))
    ISSUE(x0, y0, 0); ISSUE(x1, y1, 1); ISSUE(x2, y2, 2); ISSUE(x3, y3, 3);
    ISSUE(x4, y4, 4); ISSUE(x5, y5, 5); ISSUE(x6, y6, 6); ISSUE(x7, y7, 7);
#undef ISSUE

    // ---- phase 2: counted drains; squares as each row lands
#define WAITC(N, XV, YV)                                                    \
    asm volatile("s_waitcnt vmcnt(" N ")" : "+v"(XV), "+v"(YV))
#define SQ(S, XV, YV)                                                       \
    float S = XV[0]*XV[0] + XV[1]*XV[1] + XV[2]*XV[2] + XV[3]*XV[3]         \
            + YV[0]*YV[0] + YV[1]*YV[1] + YV[2]*YV[2] + YV[3]*YV[3]
    WAITC("14", x0, y0); SQ(s0, x0, y0);
    WAITC("12", x1, y1); SQ(s1, x1, y1);
    WAITC("10", x2, y2); SQ(s2, x2, y2);
    WAITC("8",  x3, y3); SQ(s3, x3, y3);
    WAITC("6",  x4, y4); SQ(s4, x4, y4);
    WAITC("4",  x5, y5); SQ(s5, x5, y5);
    WAITC("2",  x6, y6); SQ(s6, x6, y6);
    WAITC("0",  x7, y7); SQ(s7, x7, y7);
#undef WAITC
#undef SQ

    // ---- phase 3: 8 interleaved butterfly reductions (independent chains)
    #pragma unroll
    for (int m = 1; m < 64; m <<= 1) {
        s0 += __shfl_xor(s0, m); s1 += __shfl_xor(s1, m);
        s2 += __shfl_xor(s2, m); s3 += __shfl_xor(s3, m);
        s4 += __shfl_xor(s4, m); s5 += __shfl_xor(s5, m);
        s6 += __shfl_xor(s6, m); s7 += __shfl_xor(s7, m);
    }

    // ---- phase 4: scale + pack + swizzled store (identical formula to r8/r9)
#define STORE_ROW(XV, YV, SS, R)                                            \
    do {                                                                    \
        const float iv = 1.0f / fmaxf(sqrtf(SS), 1e-8f);                    \
        uint4 v;                                                            \
        v.x = packbf2_hw(XV[0] * iv, XV[1] * iv);                           \
        v.y = packbf2_hw(XV[2] * iv, XV[3] * iv);                           \
        v.z = packbf2_hw(YV[0] * iv, YV[1] * iv);                           \
        v.w = packbf2_hw(YV[2] * iv, YV[3] * iv);                           \
        const int row = rbase + (R);                                        \
        const int s   = (row ^ (row >> 2)) & 3;                             \
        *reinterpret_cast<uint4*>(dst + obase + (size_t)(R) * 512           \
                                  + kgrp + ((chnk ^ s) << 3)) = v;          \
    } while (0)
    STORE_ROW(x0, y0, s0, 0); STORE_ROW(x1, y1, s1, 1);
    STORE_ROW(x2, y2, s2, 2); STORE_ROW(x3, y3, s3, 3);
    STORE_ROW(x4, y4, s4, 4); STORE_ROW(x5, y5, s5, 5);
    STORE_ROW(x6, y6, s6, 6); STORE_ROW(x7, y7, s7, 7);
#undef STORE_ROW
}

// ---------------- kernel 1: bf16 GEMM + masked-max (gload_lds) ----------------
// grid 1024 (XCD-swizzled), 256 thr = 4 waves (2x2 of 64x64). 128x128 tile,
// BK=32, double-buffered LDS staged by global_load_lds dwordx4 (linear dest;
// source pre-swizzled by prep). Frag offsets identical to r5 (proven).
__global__ __launch_bounds__(256)
void sim_gemm(const ushort* __restrict__ e1n, const ushort* __restrict__ e2n,
              const int* __restrict__ m1g, const int* __restrict__ m2g,
              float* __restrict__ rowmax_p, float* __restrict__ colmax_p)
{
    const int bid = blockIdx.x;
    const int l   = ((bid & 7) << 7) | (bid >> 3);
    const int b   = l >> 4;
    const int rt  = l & 3;
    const int ct  = (l >> 2) & 3;

    const int tid  = threadIdx.x;
    const int lane = tid & 63;
    const int w    = tid >> 6;        // 0..3
    const int wm   = w >> 1;
    const int wn   = w & 1;
    const int q    = lane >> 4;
    const int ln   = lane & 15;
    const int nb   = ct * 128;

    __shared__ __align__(16) ushort sA[2][128 * 32];   // 2 x 8 KB
    __shared__ __align__(16) ushort sB[2][128 * 32];   // 2 x 8 KB
    float* spr = reinterpret_cast<float*>(&sA[0][0]);     // [2][128]
    float* spc = reinterpret_cast<float*>(&sA[0][512]);   // [2][128]
    int*   sm1 = reinterpret_cast<int*>(&sA[0][1024]);    // [128]
    int*   sm2 = reinterpret_cast<int*>(&sA[0][1280]);    // [128]

    const int rs = lane >> 2;
    const int ks = (lane & 3) * 8;
    const ushort* gA0 = e1n + ((size_t)(b * 512 + rt * 128 + 2 * w * 16 + rs)) * 512 + ks;
    const ushort* gA1 = gA0 + 16 * 512;
    const ushort* gB0 = e2n + ((size_t)(b * 512 + nb + 2 * w * 16 + rs)) * 512 + ks;
    const ushort* gB1 = gB0 + 16 * 512;
    const int dch = w * 1024;          // chunk-pair base (ushorts)

    const int sln = (ln & 3) ^ ((ln >> 2) & 3);
    int aoff[4], boff[4];
    #pragma unroll
    for (int mt = 0; mt < 4; ++mt)
        aoff[mt] = (wm * 64 + mt * 16 + ln) * 32 + ((q ^ sln) << 3);
    #pragma unroll
    for (int nt = 0; nt < 4; ++nt)
        boff[nt] = (wn * 64 + nt * 16 + ln) * 32 + ((q ^ sln) << 3);

    f32x4 acc[4][4];
    #pragma unroll
    for (int i = 0; i < 4; ++i)
        #pragma unroll
        for (int j = 0; j < 4; ++j)
            acc[i][j] = (f32x4){0.f, 0.f, 0.f, 0.f};

#define STAGE(P2, KT)                                                       \
    do {                                                                    \
        const int k32 = (KT) * 32;                                          \
        glds16(gA0 + k32, &sA[P2][dch]);                                    \
        glds16(gA1 + k32, &sA[P2][dch + 512]);                              \
        glds16(gB0 + k32, &sB[P2][dch]);                                    \
        glds16(gB1 + k32, &sB[P2][dch + 512]);                              \
    } while (0)

    STAGE(0, 0);
    BARV();

#define ITER(P, K)                                                          \
    do {                                                                    \
        if ((K) < 15) STAGE((P) ^ 1, (K) + 1);                              \
        bf16x8 af[4], bfr[4];                                               \
        _Pragma("unroll")                                                   \
        for (int mt = 0; mt < 4; ++mt)                                      \
            af[mt] = *reinterpret_cast<const bf16x8*>(&sA[P][aoff[mt]]);    \
        _Pragma("unroll")                                                   \
        for (int nt = 0; nt < 4; ++nt)                                      \
            bfr[nt] = *reinterpret_cast<const bf16x8*>(&sB[P][boff[nt]]);   \
        _Pragma("unroll")                                                   \
        for (int mt = 0; mt < 4; ++mt)                                      \
            _Pragma("unroll")                                               \
            for (int nt = 0; nt < 4; ++nt)                                  \
                acc[mt][nt] = __builtin_amdgcn_mfma_f32_16x16x32_bf16(      \
                    af[mt], bfr[nt], acc[mt][nt], 0, 0, 0);                 \
        BARV();                                                             \
    } while (0)

    for (int kk = 0; kk < 8; ++kk) {
        ITER(0, 2 * kk);
        ITER(1, 2 * kk + 1);
    }
#undef ITER
#undef STAGE

    if (tid < 128) sm1[tid] = m1g[b * 512 + rt * 128 + tid];
    else           sm2[tid - 128] = m2g[b * 512 + nb + (tid - 128)];
    BAR();

    #pragma unroll
    for (int mt = 0; mt < 4; ++mt) {
        #pragma unroll
        for (int rg = 0; rg < 4; ++rg) {
            float rm = NEGBIG;
            #pragma unroll
            for (int nt = 0; nt < 4; ++nt) {
                float v = sm2[wn * 64 + nt * 16 + ln] ? acc[mt][nt][rg] : NEGBIG;
                rm = fmaxf(rm, v);
            }
            rm = fmaxf(rm, __shfl_xor(rm, 1));
            rm = fmaxf(rm, __shfl_xor(rm, 2));
            rm = fmaxf(rm, __shfl_xor(rm, 4));
            rm = fmaxf(rm, __shfl_xor(rm, 8));
            if (ln == 0) spr[wn * 128 + wm * 64 + mt * 16 + q * 4 + rg] = rm;
        }
    }
    #pragma unroll
    for (int nt = 0; nt < 4; ++nt) {
        float cm = NEGBIG;
        #pragma unroll
        for (int mt = 0; mt < 4; ++mt)
            #pragma unroll
            for (int rg = 0; rg < 4; ++rg) {
                float v = sm1[wm * 64 + mt * 16 + q * 4 + rg] ? acc[mt][nt][rg] : NEGBIG;
                cm = fmaxf(cm, v);
            }
        cm = fmaxf(cm, __shfl_xor(cm, 16));
        cm = fmaxf(cm, __shfl_xor(cm, 32));
        if (lane < 16) spc[wm * 128 + wn * 64 + nt * 16 + ln] = cm;
    }
    BAR();
    if (tid < 128) {
        rowmax_p[((size_t)b * 4 + ct) * 512 + rt * 128 + tid] =
            fmaxf(spr[tid], spr[128 + tid]);
        colmax_p[((size_t)b * 4 + rt) * 512 + nb + tid] =
            fmaxf(spc[tid], spc[128 + tid]);
    }
}

// ---------------- fallback: r5 fused kernel (verbatim) ----------------
__global__ __launch_bounds__(256)
void sim_fused_fb(const float* __restrict__ e1, const float* __restrict__ e2,
                  const int* __restrict__ m1g, const int* __restrict__ m2g,
                  float* __restrict__ rowmax_p, float* __restrict__ colmax_p)
{
    const int bid = blockIdx.x;
    const int l   = ((bid & 7) << 7) | (bid >> 3);
    const int b   = l >> 4;
    const int rt  = l & 3;
    const int ct  = (l >> 2) & 3;

    const int tid = threadIdx.x;
    const int lane = tid & 63;
    const int w    = tid >> 6;
    const int wm   = w >> 1;
    const int wn   = w & 1;
    const int q    = lane >> 4;
    const int ln   = lane & 15;
    const int nb   = ct * 128;

    __shared__ __align__(16) ushort sA[2][128 * 32];
    __shared__ __align__(16) ushort sB[2][128 * 32];
    float* spr   = reinterpret_cast<float*>(&sA[0][0]);
    float* spc   = reinterpret_cast<float*>(&sA[0][512]);
    int*   sm1   = reinterpret_cast<int*>(&sA[0][1024]);
    int*   sm2   = reinterpret_cast<int*>(&sA[0][1280]);
    float* sinv1 = reinterpret_cast<float*>(&sB[0][0]);
    float* sinv2 = reinterpret_cast<float*>(&sB[0][256]);

    const int r = tid >> 1;
    const int h = tid & 1;
    const int s = (r ^ (r >> 2)) & 3;
    const float* gA = e1 + ((size_t)(b * 512 + rt * 128 + r)) * 512 + h * 16;
    const float* gB = e2 + ((size_t)(b * 512 + nb + r)) * 512 + h * 16;
    const int wo0 = r * 32 + (((2 * h)     ^ s) << 3);
    const int wo1 = r * 32 + (((2 * h + 1) ^ s) << 3);

    const int sln = (ln & 3) ^ ((ln >> 2) & 3);
    int aoff[4], boff[4];
    #pragma unroll
    for (int mt = 0; mt < 4; ++mt)
        aoff[mt] = (wm * 64 + mt * 16 + ln) * 32 + ((q ^ sln) << 3);
    #pragma unroll
    for (int nt = 0; nt < 4; ++nt)
        boff[nt] = (wn * 64 + nt * 16 + ln) * 32 + ((q ^ sln) << 3);

    float ssA = 0.f, ssB = 0.f;
    float4 ra[2][4], rb[2][4];

    auto LOADK = [&](int u, int kf) {
        const float4* pa = reinterpret_cast<const float4*>(gA + kf);
        const float4* pb = reinterpret_cast<const float4*>(gB + kf);
        ra[u][0] = pa[0]; ra[u][1] = pa[1]; ra[u][2] = pa[2]; ra[u][3] = pa[3];
        rb[u][0] = pb[0]; rb[u][1] = pb[1]; rb[u][2] = pb[2]; rb[u][3] = pb[3];
    };
    auto CVTWRITE = [&](int u, int pd) {
        #pragma unroll
        for (int i = 0; i < 4; ++i) {
            ssA += ra[u][i].x * ra[u][i].x + ra[u][i].y * ra[u][i].y
                 + ra[u][i].z * ra[u][i].z + ra[u][i].w * ra[u][i].w;
            ssB += rb[u][i].x * rb[u][i].x + rb[u][i].y * rb[u][i].y
                 + rb[u][i].z * rb[u][i].z + rb[u][i].w * rb[u][i].w;
        }
        uint4 v;
        v.x = packbf2_hw(ra[u][0].x, ra[u][0].y); v.y = packbf2_hw(ra[u][0].z, ra[u][0].w);
        v.z = packbf2_hw(ra[u][1].x, ra[u][1].y); v.w = packbf2_hw(ra[u][1].z, ra[u][1].w);
        *reinterpret_cast<uint4*>(&sA[pd][wo0]) = v;
        v.x = packbf2_hw(ra[u][2].x, ra[u][2].y); v.y = packbf2_hw(ra[u][2].z, ra[u][2].w);
        v.z = packbf2_hw(ra[u][3].x, ra[u][3].y); v.w = packbf2_hw(ra[u][3].z, ra[u][3].w);
        *reinterpret_cast<uint4*>(&sA[pd][wo1]) = v;
        v.x = packbf2_hw(rb[u][0].x, rb[u][0].y); v.y = packbf2_hw(rb[u][0].z, rb[u][0].w);
        v.z = packbf2_hw(rb[u][1].x, rb[u][1].y); v.w = packbf2_hw(rb[u][1].z, rb[u][1].w);
        *reinterpret_cast<uint4*>(&sB[pd][wo0]) = v;
        v.x = packbf2_hw(rb[u][2].x, rb[u][2].y); v.y = packbf2_hw(rb[u][2].z, rb[u][2].w);
        v.z = packbf2_hw(rb[u][3].x, rb[u][3].y); v.w = packbf2_hw(rb[u][3].z, rb[u][3].w);
        *reinterpret_cast<uint4*>(&sB[pd][wo1]) = v;
    };

    f32x4 acc[4][4];
    #pragma unroll
    for (int i = 0; i < 4; ++i)
        #pragma unroll
        for (int j = 0; j < 4; ++j)
            acc[i][j] = (f32x4){0.f, 0.f, 0.f, 0.f};

    LOADK(0, 0);
    CVTWRITE(0, 0);
    LOADK(1, 32);
    BAR();

#define HALF_ITER(P, K)                                                    \
    do {                                                                   \
        if ((K) < 14) LOADK(P, ((K) + 2) * 32);                            \
        bf16x8 af[4], bfr[4];                                              \
        _Pragma("unroll")                                                  \
        for (int mt = 0; mt < 4; ++mt)                                     \
            af[mt] = *reinterpret_cast<const bf16x8*>(&sA[P][aoff[mt]]);   \
        _Pragma("unroll")                                                  \
        for (int nt = 0; nt < 4; ++nt)                                     \
            bfr[nt] = *reinterpret_cast<const bf16x8*>(&sB[P][boff[nt]]);  \
        if ((K) < 15) CVTWRITE((P) ^ 1, (P) ^ 1);                          \
        _Pragma("unroll")                                                  \
        for (int mt = 0; mt < 4; ++mt)                                     \
            _Pragma("unroll")                                              \
            for (int nt = 0; nt < 4; ++nt)                                 \
                acc[mt][nt] = __builtin_amdgcn_mfma_f32_16x16x32_bf16(     \
                    af[mt], bfr[nt], acc[mt][nt], 0, 0, 0);                \
        BAR();                                                             \
    } while (0)

    for (int kk = 0; kk < 8; ++kk) {
        HALF_ITER(0, 2 * kk);
        HALF_ITER(1, 2 * kk + 1);
    }
#undef HALF_ITER

    if (tid < 128) sm1[tid] = m1g[b * 512 + rt * 128 + tid];
    else           sm2[tid - 128] = m2g[b * 512 + nb + (tid - 128)];
    ssA += __shfl_xor(ssA, 1);
    ssB += __shfl_xor(ssB, 1);
    if (h == 0) {
        sinv1[r] = 1.0f / fmaxf(sqrtf(ssA), 1e-8f);
        sinv2[r] = 1.0f / fmaxf(sqrtf(ssB), 1e-8f);
    }
    BAR();

    float invj[4];
    f32x4 invi[4];
    #pragma unroll
    for (int nt = 0; nt < 4; ++nt)
        invj[nt] = sinv2[wn * 64 + nt * 16 + ln];
    #pragma unroll
    for (int mt = 0; mt < 4; ++mt)
        #pragma unroll
        for (int rg = 0; rg < 4; ++rg)
            invi[mt][rg] = sinv1[wm * 64 + mt * 16 + q * 4 + rg];
    #pragma unroll
    for (int mt = 0; mt < 4; ++mt)
        #pragma unroll
        for (int nt = 0; nt < 4; ++nt)
            acc[mt][nt] = acc[mt][nt] * (invi[mt] * invj[nt]);

    #pragma unroll
    for (int mt = 0; mt < 4; ++mt) {
        #pragma unroll
        for (int rg = 0; rg < 4; ++rg) {
            float rm = NEGBIG;
            #pragma unroll
            for (int nt = 0; nt < 4; ++nt) {
                float v = sm2[wn * 64 + nt * 16 + ln] ? acc[mt][nt][rg] : NEGBIG;
                rm = fmaxf(rm, v);
            }
            rm = fmaxf(rm, __shfl_xor(rm, 1));
            rm = fmaxf(rm, __shfl_xor(rm, 2));
            rm = fmaxf(rm, __shfl_xor(rm, 4));
            rm = fmaxf(rm, __shfl_xor(rm, 8));
            if (ln == 0) spr[wn * 128 + wm * 64 + mt * 16 + q * 4 + rg] = rm;
        }
    }
    #pragma unroll
    for (int nt = 0; nt < 4; ++nt) {
        float cm = NEGBIG;
        #pragma unroll
        for (int mt = 0; mt < 4; ++mt)
            #pragma unroll
            for (int rg = 0; rg < 4; ++rg) {
                float v = sm1[wm * 64 + mt * 16 + q * 4 + rg] ? acc[mt][nt][rg] : NEGBIG;
                cm = fmaxf(cm, v);
            }
        cm = fmaxf(cm, __shfl_xor(cm, 16));
        cm = fmaxf(cm, __shfl_xor(cm, 32));
        if (lane < 16) spc[wm * 128 + wn * 64 + nt * 16 + ln] = cm;
    }
    BAR();
    if (tid < 128) {
        rowmax_p[((size_t)b * 4 + ct) * 512 + rt * 128 + tid] =
            fmaxf(spr[tid], spr[128 + tid]);
        colmax_p[((size_t)b * 4 + rt) * 512 + nb + tid] =
            fmaxf(spc[tid], spc[128 + tid]);
    }
}

// ---------------- kernel 2: per-batch final reduction ----------------
__global__ __launch_bounds__(256)
void final_kernel(const int* __restrict__ m1g, const int* __restrict__ m2g,
                  const float* __restrict__ rowmax_p, const float* __restrict__ colmax_p,
                  float* __restrict__ out)
{
    const int b = blockIdx.x;
    const int tid = threadIdx.x;
    const int lane = tid & 63;
    const int w = tid >> 6;

    float sum = 0.f;
    float nn  = 0.f;
    for (int j = tid; j < 512; j += 256) {
        int mm1 = m1g[b * 512 + j];
        int mm2 = m2g[b * 512 + j];
        nn += (float)(mm1 + mm2);
        const float* rp = rowmax_p + (size_t)b * 2048 + j;
        float rm = fmaxf(fmaxf(rp[0], rp[512]), fmaxf(rp[1024], rp[1536]));
        if (mm1) sum += rm;
        const float* cp = colmax_p + (size_t)b * 2048 + j;
        float cm = fmaxf(fmaxf(cp[0], cp[512]), fmaxf(cp[1024], cp[1536]));
        if (mm2) sum += cm;
    }
    #pragma unroll
    for (int m = 32; m; m >>= 1) {
        sum += __shfl_xor(sum, m);
        nn  += __shfl_xor(nn, m);
    }
    __shared__ float ssum[4], snn[4];
    if (lane == 0) { ssum[w] = sum; snn[w] = nn; }
    __syncthreads();
    if (tid == 0) {
        float S = ssum[0] + ssum[1] + ssum[2] + ssum[3];
        float N = snn[0] + snn[1] + snn[2] + snn[3];
        out[b] = S / N;
    }
}

extern "C" void kernel_launch(void* const* d_in, const int* in_sizes, int n_in,
                              void* d_out, int out_size, void* d_ws, size_t ws_size,
                              hipStream_t stream) {
    const float* e1 = (const float*)d_in[0];
    const float* e2 = (const float*)d_in[1];
    const int*   m1 = (const int*)d_in[2];
    const int*   m2 = (const int*)d_in[3];
    float* out = (float*)d_out;

    float* ws = (float*)d_ws;
    float* rowmax_p = ws;                 // 64*4*512 floats
    float* colmax_p = ws + 131072;        // 64*4*512 floats

    const size_t PANEL = (size_t)64 * 512 * 512;            // ushort count
    const size_t NEED  = 1048576 + 2 * PANEL * sizeof(ushort);  // ~68.1 MB

    if (ws_size >= NEED) {
        ushort* e1n = (ushort*)((char*)d_ws + 1048576);
        ushort* e2n = e1n + PANEL;
        prep_kernel<<<dim3(2048), 256, 0, stream>>>(e1, e2, e1n, e2n);
        sim_gemm<<<dim3(1024), 256, 0, stream>>>(e1n, e2n, m1, m2,
                                                 rowmax_p, colmax_p);
    } else {
        sim_fused_fb<<<dim3(1024), 256, 0, stream>>>(e1, e2, m1, m2,
                                                     rowmax_p, colmax_p);
    }
    final_kernel<<<64, 256, 0, stream>>>(m1, m2, rowmax_p, colmax_p, out);
}